// Round 1
// baseline (220.161 us; speedup 1.0000x reference)
//
#include <hip/hip_runtime.h>

// Problem constants
#define N_B   4
#define N_T   16
#define N_Y   256
#define N_X   256
#define PIX   65536        // N_Y*N_X
#define SLABF 1048576      // floats per slab per batch = 16*65536
#define BATCHF 7340032     // floats per batch input  = 112*65536

// Output float offsets
#define KAPPA_BASE 0
#define M_BASE     4194304
#define H_BASE     12582912
#define TAU_BASE   29360128

__device__ __forceinline__ float sp10(float x) {
    // softplus(10x)/10, numerically stable
    float z = 10.0f * x;
    float r = fmaxf(z, 0.0f) + log1pf(__expf(-fabsf(z)));
    return r * 0.1f;
}

__global__ __launch_bounds__(256)
void decode_param_kernel(const float* __restrict__ p, float* __restrict__ out) {
    // LDS: per-t rows of 64 x-values, padded row stride 68 floats
    // (phase-1 float4 writes aligned; phase-2 column reads only 2-way conflicts = free)
    __shared__ float l00[N_T][68];
    __shared__ float l01[N_T][68];
    __shared__ float l11[N_T][68];

    const int bid = blockIdx.x;
    const int tid = threadIdx.x;

    if (bid < 4096) {
        // ---- H blocks: one (b, y, 64-wide x tile) each ----
        const int xt = bid & 3;          // x tile 0..3
        const int y  = (bid >> 2) & 255; // row
        const int b  = bid >> 10;        // batch
        const int t  = tid >> 4;         // 0..15
        const int xq = tid & 15;         // 0..15 -> x-local quad

        const long inbase = (long)b * BATCHF + (long)y * N_X + xt * 64 + xq * 4;
        const float4 g4  = *reinterpret_cast<const float4*>(p + inbase + (long)(48 + t) * PIX);
        const float4 vx4 = *reinterpret_cast<const float4*>(p + inbase + (long)(64 + t) * PIX);
        const float4 vy4 = *reinterpret_cast<const float4*>(p + inbase + (long)(80 + t) * PIX);

        float4 h00, h01, h11;
        {
            float g0 = sp10(g4.x), g1 = sp10(g4.y), g2 = sp10(g4.z), g3 = sp10(g4.w);
            h00 = make_float4(g0 + vx4.x * vx4.x, g1 + vx4.y * vx4.y,
                              g2 + vx4.z * vx4.z, g3 + vx4.w * vx4.w);
            h01 = make_float4(vx4.x * vy4.x, vx4.y * vy4.y,
                              vx4.z * vy4.z, vx4.w * vy4.w);
            h11 = make_float4(g0 + vy4.x * vy4.x, g1 + vy4.y * vy4.y,
                              g2 + vy4.z * vy4.z, g3 + vy4.w * vy4.w);
        }
        *reinterpret_cast<float4*>(&l00[t][xq * 4]) = h00;
        *reinterpret_cast<float4*>(&l01[t][xq * 4]) = h01;
        *reinterpret_cast<float4*>(&l11[t][xq * 4]) = h11;
        __syncthreads();

        // phase 2: each thread emits one float4 along t for one x
        const int xl = tid >> 2;          // 0..63 (x local)
        const int tq = (tid & 3) * 4;     // 0,4,8,12

        float4 o00 = make_float4(l00[tq + 0][xl], l00[tq + 1][xl], l00[tq + 2][xl], l00[tq + 3][xl]);
        float4 o01 = make_float4(l01[tq + 0][xl], l01[tq + 1][xl], l01[tq + 2][xl], l01[tq + 3][xl]);
        float4 o11 = make_float4(l11[tq + 0][xl], l11[tq + 1][xl], l11[tq + 2][xl], l11[tq + 3][xl]);

        const long outoff = (long)H_BASE + (long)b * 4194304 + (long)y * 4096
                          + xt * 1024 + xl * 16 + tq;
        *reinterpret_cast<float4*>(out + outoff)           = o00;  // H00
        *reinterpret_cast<float4*>(out + outoff + 1048576) = o01;  // H01
        *reinterpret_cast<float4*>(out + outoff + 2097152) = o01;  // H10 (== H01)
        *reinterpret_cast<float4*>(out + outoff + 3145728) = o11;  // H11
    } else {
        // ---- elementwise blocks: kappa / m-copy / tau ----
        // 16 jobs of 2^18 float4 each: job = b*4 + kind
        const long j   = (long)(bid - 4096) * 256 + tid;  // 0 .. 4194303
        const int job  = (int)(j >> 18);
        const long r   = j & 262143;
        const int b    = job >> 2;
        const int kind = job & 3;

        const long inb = (long)b * (BATCHF / 4);
        long in4, out4;
        bool do_sp;
        if (kind == 0)      { in4 = inb;           out4 = (long)b * 262144;                 do_sp = true;  } // kappa
        else if (kind == 1) { in4 = inb + 262144;  out4 = M_BASE / 4 + (long)b * 524288;    do_sp = false; } // m c=0
        else if (kind == 2) { in4 = inb + 524288;  out4 = M_BASE / 4 + 262144 + (long)b * 524288; do_sp = false; } // m c=1
        else                { in4 = inb + 1572864; out4 = TAU_BASE / 4 + (long)b * 262144;  do_sp = true;  } // tau

        float4 v = *reinterpret_cast<const float4*>(p + (in4 + r) * 4);
        if (do_sp) {
            v.x = sp10(v.x); v.y = sp10(v.y); v.z = sp10(v.z); v.w = sp10(v.w);
        }
        *reinterpret_cast<float4*>(out + (out4 + r) * 4) = v;
    }
}

extern "C" void kernel_launch(void* const* d_in, const int* in_sizes, int n_in,
                              void* d_out, int out_size, void* d_ws, size_t ws_size,
                              hipStream_t stream) {
    const float* p = (const float*)d_in[0];
    float* out = (float*)d_out;
    // 4096 H blocks + 16384 elementwise blocks
    decode_param_kernel<<<20480, 256, 0, stream>>>(p, out);
}